// Round 11
// baseline (267.956 us; speedup 1.0000x reference)
//
#include <hip/hip_runtime.h>

typedef unsigned short u16;
typedef unsigned int u32;
typedef __attribute__((ext_vector_type(8))) short short8;
typedef __attribute__((ext_vector_type(4))) float f32x4;
typedef __attribute__((ext_vector_type(2))) u32 uintx2;
typedef __attribute__((address_space(3))) u32 lds32;
typedef const __attribute__((address_space(1))) u32 g32c;

__device__ __forceinline__ u16 f2bf(float f) {
  union { float f; u32 u; } v; v.f = f;
  return (u16)((v.u + 0x7fffu + ((v.u >> 16) & 1u)) >> 16);  // RNE
}
__device__ __forceinline__ float bf2f(u16 h) {
  union { u32 u; float f; } v; v.u = ((u32)h) << 16;
  return v.f;
}

// ---------------- weight convert: 4x [512x512] f32 -> bf16 ----------------
__global__ void cvt_w_kernel(const float* __restrict__ Wq, const float* __restrict__ Wk,
                             const float* __restrict__ Wv, const float* __restrict__ Wo,
                             u16* __restrict__ dst) {
  int m = blockIdx.y;
  const float* s = (m == 0) ? Wq : (m == 1) ? Wk : (m == 2) ? Wv : Wo;
  int idx = (blockIdx.x * 256 + threadIdx.x) * 4;
  float4 v = *(const float4*)(s + idx);
  uintx2 pk;
  pk[0] = (u32)f2bf(v.x) | ((u32)f2bf(v.y) << 16);
  pk[1] = (u32)f2bf(v.z) | ((u32)f2bf(v.w) << 16);
  *(uintx2*)(dst + m * 262144 + idx) = pk;
}

// ======================= async-pipelined BT GEMMs =======================
// 128x128 tile, BK=64, 4 waves, LDS double-buffered; staging issued EARLY in
// each phase, FULL drain (vmcnt(0) lgkmcnt(0)) before the phase barrier --
// sound regardless of compiler issue order (round-10 lesson: counted vmcnt
// without sched_barrier pinning is unsound for compiler-reorderable loads).

// shared compute step: 32 MFMA on ldsA/ldsB tile (swizzled reads)
__device__ __forceinline__ void gemm_tile_mfma(const u16* bA, const u16* bB, int wr, int wc,
                                               int lr, int lg, f32x4 (&acc)[4][4]) {
#pragma unroll
  for (int kk = 0; kk < 2; ++kk) {
    short8 af[4], bfr[4];
#pragma unroll
    for (int mf = 0; mf < 4; ++mf) {
      int row = wr + mf * 16 + lr;
      af[mf] = *(const short8*)&bA[row * 64 + (((kk * 4 + lg) ^ (row & 7)) * 8)];
    }
#pragma unroll
    for (int nf = 0; nf < 4; ++nf) {
      int row = wc + nf * 16 + lr;
      bfr[nf] = *(const short8*)&bB[row * 64 + (((kk * 4 + lg) ^ (row & 7)) * 8)];
    }
#pragma unroll
    for (int mf = 0; mf < 4; ++mf)
#pragma unroll
      for (int nf = 0; nf < 4; ++nf)
        acc[mf][nf] =
            __builtin_amdgcn_mfma_f32_16x16x32_bf16(af[mf], bfr[nf], acc[mf][nf], 0, 0, 0);
  }
}

// ---- gemm3: A = f32 (Q or K), reg-staged with cvt; B via gload_lds ----
// TRANSV: write output transposed per head (V projection).
template <bool TRANSV>
__device__ __forceinline__ void gemm_f32a_body(const float* __restrict__ Ap,
                                               const u16* __restrict__ Bw,
                                               const float* __restrict__ bias,
                                               u16* __restrict__ C) {
  __shared__ __align__(16) u16 ldsA[2][128 * 64];
  __shared__ __align__(16) u16 ldsB[2][128 * 64];
  const int t = threadIdx.x;
  const int lane = t & 63, wid = t >> 6;
  const int lr = lane & 15, lg = lane >> 4;
  const int n0 = blockIdx.x * 128;
  const int m0 = blockIdx.y * 128;
  const int wr = (wid >> 1) * 64, wc = (wid & 1) * 64;
  const int wslot = (t & 192) * 8;  // wave-uniform LDS element base per i-slab

  // per-thread staging coordinates (4 slabs of 256 threads)
  int arow[4], apu[4];
  const u16* bsrc[4];
  const float* asrc[4];
#pragma unroll
  for (int i = 0; i < 4; ++i) {
    int lin = i * 256 + t;
    int row = lin >> 3, u = lin & 7;
    arow[i] = row;
    apu[i] = u ^ (row & 7);
    asrc[i] = Ap + (size_t)(m0 + row) * 512 + u * 8;
    bsrc[i] = Bw + (size_t)(n0 + row) * 512 + ((u ^ (row & 7)) * 8);  // pre-swizzled
  }

  f32x4 acc[4][4];
#pragma unroll
  for (int i = 0; i < 4; ++i)
#pragma unroll
    for (int j = 0; j < 4; ++j)
#pragma unroll
      for (int r = 0; r < 4; ++r) acc[i][j][r] = 0.f;

  float4 rA[2][8];  // 2-deep raw A prefetch; all indices static post-unroll

#define BISSUE(bu, kt)                                                                      \
  do {                                                                                      \
    _Pragma("unroll") for (int i_ = 0; i_ < 4; ++i_) {                                      \
      __builtin_amdgcn_global_load_lds((g32c*)(bsrc[i_] + (kt)),                            \
                                       (lds32*)(&ldsB[bu][i_ * 2048 + wslot]), 16, 0, 0);   \
    }                                                                                       \
  } while (0)
#define AISSUE(set, kt)                                                                     \
  do {                                                                                      \
    _Pragma("unroll") for (int i_ = 0; i_ < 4; ++i_) {                                      \
      rA[set][2 * i_] = *(const float4*)(asrc[i_] + (kt));                                  \
      rA[set][2 * i_ + 1] = *(const float4*)(asrc[i_] + (kt) + 4);                          \
    }                                                                                       \
  } while (0)
#define AWRITE(set, bu)                                                                     \
  do {                                                                                      \
    _Pragma("unroll") for (int i_ = 0; i_ < 4; ++i_) {                                      \
      float4 v0 = rA[set][2 * i_], v1 = rA[set][2 * i_ + 1];                                \
      short8 pk;                                                                            \
      pk[0] = (short)f2bf(v0.x); pk[1] = (short)f2bf(v0.y);                                 \
      pk[2] = (short)f2bf(v0.z); pk[3] = (short)f2bf(v0.w);                                 \
      pk[4] = (short)f2bf(v1.x); pk[5] = (short)f2bf(v1.y);                                 \
      pk[6] = (short)f2bf(v1.z); pk[7] = (short)f2bf(v1.w);                                 \
      *(short8*)&ldsA[bu][arow[i_] * 64 + apu[i_] * 8] = pk;                                \
    }                                                                                       \
  } while (0)
#define DRAINBAR()                                                     \
  do {                                                                 \
    asm volatile("s_waitcnt vmcnt(0) lgkmcnt(0)" ::: "memory");        \
    __builtin_amdgcn_s_barrier();                                      \
  } while (0)

  // prologue: B(0) DMA; A(0) -> regs -> cvt -> LDS; A(1) -> regs; full drain.
  BISSUE(0, 0);
  AISSUE(0, 0);
  AWRITE(0, 0);
  AISSUE(1, 64);
  DRAINBAR();

#pragma unroll
  for (int p = 0; p < 8; ++p) {
    const int buf = p & 1, nbuf = buf ^ 1;
    if (p < 7) {
      BISSUE(nbuf, (p + 1) * 64);              // B(p+1) DMA; overlaps compute below
      AWRITE((p + 1) & 1, nbuf);               // cvt+write A(p+1) (regs already drained)
      if (p < 6) AISSUE(p & 1, (p + 2) * 64);  // A(p+2) raw loads; overlap compute
    }
    gemm_tile_mfma(&ldsA[buf][0], &ldsB[buf][0], wr, wc, lr, lg, acc);
    if (p < 7) DRAINBAR();  // full drain: sound for any compiler issue order
  }
#undef BISSUE
#undef AISSUE
#undef AWRITE
#undef DRAINBAR

  if constexpr (TRANSV) {
    const int h_ = n0 >> 7;
#pragma unroll
    for (int mf = 0; mf < 4; ++mf)
#pragma unroll
      for (int nf = 0; nf < 4; ++nf) {
        int d = wc + nf * 16 + lr;
        int rr0 = m0 + wr + mf * 16 + lg * 4;
        int b_ = rr0 >> 10;
        int k0 = rr0 & 1023;
        float bvv = bias[n0 + d];
        uintx2 pk;
        pk[0] = (u32)f2bf(acc[mf][nf][0] + bvv) | ((u32)f2bf(acc[mf][nf][1] + bvv) << 16);
        pk[1] = (u32)f2bf(acc[mf][nf][2] + bvv) | ((u32)f2bf(acc[mf][nf][3] + bvv) << 16);
        *(uintx2*)(C + (((size_t)b_ * 4 + h_) * 128 + d) * 1024 + k0) = pk;
      }
  } else {
#pragma unroll
    for (int mf = 0; mf < 4; ++mf)
#pragma unroll
      for (int nf = 0; nf < 4; ++nf) {
        int c = n0 + wc + nf * 16 + lr;
        float bv = bias[c];
#pragma unroll
        for (int r = 0; r < 4; ++r) {
          int rr = m0 + wr + mf * 16 + lg * 4 + r;  // C/D: col=lane&15, row=(lane>>4)*4+reg
          C[(size_t)rr * 512 + c] = f2bf(acc[mf][nf][r] + bv);
        }
      }
  }
}

__global__ __launch_bounds__(256) void gemm3_kernel(const float* __restrict__ Q,
                                                    const float* __restrict__ K,
                                                    const u16* __restrict__ Wb,
                                                    const float* __restrict__ bq,
                                                    const float* __restrict__ bk,
                                                    const float* __restrict__ bv,
                                                    u16* qb, u16* kb, u16* vbT) {
  int z = blockIdx.z;
  if (z == 2) {
    gemm_f32a_body<true>(K, Wb + 524288, bv, vbT);
  } else if (z == 1) {
    gemm_f32a_body<false>(K, Wb + 262144, bk, kb);
  } else {
    gemm_f32a_body<false>(Q, Wb, bq, qb);
  }
}

// ---- gemmo: A = bf16 (X), both operands via gload_lds; Z = X + relu(XWo^T+bo) ----
__global__ __launch_bounds__(256) void gemmo_kernel(const u16* __restrict__ X,
                                                    const u16* __restrict__ Wb,
                                                    const float* __restrict__ bo,
                                                    u16* __restrict__ Z) {
  __shared__ __align__(16) u16 ldsA[2][128 * 64];
  __shared__ __align__(16) u16 ldsB[2][128 * 64];
  const int t = threadIdx.x;
  const int lane = t & 63, wid = t >> 6;
  const int lr = lane & 15, lg = lane >> 4;
  const int n0 = blockIdx.x * 128;
  const int m0 = blockIdx.y * 128;
  const int wr = (wid >> 1) * 64, wc = (wid & 1) * 64;
  const int wslot = (t & 192) * 8;

  const u16* asrc[4];
  const u16* bsrc[4];
#pragma unroll
  for (int i = 0; i < 4; ++i) {
    int lin = i * 256 + t;
    int row = lin >> 3, u = lin & 7;
    int pu = (u ^ (row & 7)) * 8;  // pre-swizzled source slot
    asrc[i] = X + (size_t)(m0 + row) * 512 + pu;
    bsrc[i] = Wb + (size_t)(n0 + row) * 512 + pu;
  }

  f32x4 acc[4][4];
#pragma unroll
  for (int i = 0; i < 4; ++i)
#pragma unroll
    for (int j = 0; j < 4; ++j)
#pragma unroll
      for (int r = 0; r < 4; ++r) acc[i][j][r] = 0.f;

#define STAGEO(bu, kt)                                                                      \
  do {                                                                                      \
    _Pragma("unroll") for (int i_ = 0; i_ < 4; ++i_) {                                      \
      __builtin_amdgcn_global_load_lds((g32c*)(asrc[i_] + (kt)),                            \
                                       (lds32*)(&ldsA[bu][i_ * 2048 + wslot]), 16, 0, 0);   \
      __builtin_amdgcn_global_load_lds((g32c*)(bsrc[i_] + (kt)),                            \
                                       (lds32*)(&ldsB[bu][i_ * 2048 + wslot]), 16, 0, 0);   \
    }                                                                                       \
  } while (0)

  STAGEO(0, 0);
  asm volatile("s_waitcnt vmcnt(0)" ::: "memory");
  __builtin_amdgcn_s_barrier();

#pragma unroll
  for (int p = 0; p < 8; ++p) {
    const int buf = p & 1, nbuf = buf ^ 1;
    if (p < 7) STAGEO(nbuf, (p + 1) * 64);  // in flight across the compute below
    gemm_tile_mfma(&ldsA[buf][0], &ldsB[buf][0], wr, wc, lr, lg, acc);
    if (p < 7) {
      asm volatile("s_waitcnt vmcnt(0)" ::: "memory");
      __builtin_amdgcn_s_barrier();
    }
  }
#undef STAGEO

#pragma unroll
  for (int mf = 0; mf < 4; ++mf)
#pragma unroll
    for (int nf = 0; nf < 4; ++nf) {
      int c = n0 + wc + nf * 16 + lr;
      float bv = bo[c];
#pragma unroll
      for (int r = 0; r < 4; ++r) {
        int rr = m0 + wr + mf * 16 + lg * 4 + r;
        float v = acc[mf][nf][r] + bv;
        v = v > 0.f ? v : 0.f;
        v += bf2f(X[(size_t)rr * 512 + c]);
        Z[(size_t)rr * 512 + c] = f2bf(v);
      }
    }
}

// ---------------- fused attention (round-9, frozen) ----------------
__global__ __launch_bounds__(256) void attn_kernel(const u16* __restrict__ qb,
                                                   const u16* __restrict__ kb,
                                                   const u16* __restrict__ vbT,
                                                   const float* __restrict__ Wt,
                                                   u16* __restrict__ Ob) {
  __shared__ __align__(16) u16 ldsK[2][64 * 128];
  __shared__ __align__(16) u16 ldsVT[2][128 * 64];
  __shared__ __align__(16) u16 ldsP[128 * 64];
  const int t = threadIdx.x;
  const int lane = t & 63, wid = t >> 6;
  const int lr = lane & 15, lg = lane >> 4;
  const int bid = blockIdx.x;
  const int x_ = bid & 7, s_ = bid >> 3;
  const int hb = ((s_ & 7) << 3) | x_;  // h*16 + b
  const int q0 = (s_ >> 3) * 128;
  const int b = hb & 15;
  const int h = hb >> 4;
  const int wq = wid * 32;
  const size_t kvbase = ((size_t)b * 1024) * 512 + h * 128;
  const size_t vtbase = ((size_t)b * 4 + h) * 131072;  // V^T [128 d][1024 k]
  const float SCALE = 0.044194173824159216f;           // 1/sqrt(512)

  const u16* ksrc[4];
  const u16* vtsrc[4];
#pragma unroll
  for (int i = 0; i < 4; ++i) {
    {
      int lin = i * 256 + t;
      int row = lin >> 4, u = lin & 15;
      ksrc[i] = kb + kvbase + (size_t)row * 512 + ((u ^ (row & 15)) * 8);
    }
    {
      int lin = i * 256 + t;
      int row = lin >> 3, u = lin & 7;
      vtsrc[i] = vbT + vtbase + (size_t)row * 1024 + ((u ^ (row & 7)) * 8);
    }
  }
  const int wslot = (t & 192) * 8;

#define STAGE(bu)                                                                           \
  do {                                                                                      \
    _Pragma("unroll") for (int i_ = 0; i_ < 4; ++i_) {                                      \
      __builtin_amdgcn_global_load_lds((g32c*)(ksrc[i_]),                                   \
                                       (lds32*)(&ldsK[bu][i_ * 2048 + wslot]), 16, 0, 0);   \
      __builtin_amdgcn_global_load_lds((g32c*)(vtsrc[i_]),                                  \
                                       (lds32*)(&ldsVT[bu][i_ * 2048 + wslot]), 16, 0, 0);  \
      ksrc[i_] += 32768;                                                                    \
      vtsrc[i_] += 64;                                                                      \
    }                                                                                       \
  } while (0)

  const float* wp0 = Wt + ((size_t)hb * 1024 + q0 + wq + lr) * 1024 + lg * 4;
  const float* wp1 = wp0 + 16 * 1024;

#define WLOADP(W)                                          \
  do {                                                     \
    _Pragma("unroll") for (int j_ = 0; j_ < 4; ++j_) {     \
      W[j_]     = *(const f32x4*)(wp0 + j_ * 16);          \
      W[4 + j_] = *(const f32x4*)(wp1 + j_ * 16);          \
    }                                                      \
    wp0 += 64; wp1 += 64;                                  \
  } while (0)

  short8 qfr[2][4];
#pragma unroll
  for (int nf = 0; nf < 2; ++nf) {
    const u16* qp = qb + kvbase + (size_t)(q0 + wq + nf * 16 + lr) * 512 + lg * 8;
#pragma unroll
    for (int ds = 0; ds < 4; ++ds) qfr[nf][ds] = *(const short8*)(qp + ds * 32);
  }

  f32x4 oacc[2][8];
#pragma unroll
  for (int i = 0; i < 2; ++i)
#pragma unroll
    for (int j = 0; j < 8; ++j)
#pragma unroll
      for (int r = 0; r < 4; ++r) oacc[i][j][r] = 0.f;
  float lacc[2] = {0.f, 0.f};

  auto tile_compute = [&](const u16* bK, const u16* bVT, const f32x4 (&W)[8]) {
    f32x4 sacc[4][2];
#pragma unroll
    for (int i = 0; i < 4; ++i)
#pragma unroll
      for (int j = 0; j < 2; ++j)
#pragma unroll
        for (int r = 0; r < 4; ++r) sacc[i][j][r] = 0.f;

#pragma unroll
    for (int ds = 0; ds < 4; ++ds) {
      short8 kf[4];
#pragma unroll
      for (int mf = 0; mf < 4; ++mf) {
        int row = mf * 16 + lr;
        kf[mf] = *(const short8*)&bK[row * 128 + (((ds * 4 + lg) ^ (row & 15)) * 8)];
      }
      __builtin_amdgcn_s_setprio(1);
#pragma unroll
      for (int mf = 0; mf < 4; ++mf)
#pragma unroll
        for (int nf = 0; nf < 2; ++nf)
          sacc[mf][nf] =
              __builtin_amdgcn_mfma_f32_16x16x32_bf16(kf[mf], qfr[nf][ds], sacc[mf][nf], 0, 0, 0);
      __builtin_amdgcn_s_setprio(0);
    }

#pragma unroll
    for (int nf = 0; nf < 2; ++nf) {
      int prow = wq + nf * 16 + lr;
#pragma unroll
      for (int mf = 0; mf < 4; ++mf) {
        f32x4 w4 = W[nf * 4 + mf];
        float p0 = w4[0] * __expf(sacc[mf][nf][0] * SCALE);
        float p1 = w4[1] * __expf(sacc[mf][nf][1] * SCALE);
        float p2 = w4[2] * __expf(sacc[mf][nf][2] * SCALE);
        float p3 = w4[3] * __expf(sacc[mf][nf][3] * SCALE);
        lacc[nf] += (p0 + p1) + (p2 + p3);
        uintx2 pk;
        pk[0] = (u32)f2bf(p0) | ((u32)f2bf(p1) << 16);
        pk[1] = (u32)f2bf(p2) | ((u32)f2bf(p3) << 16);
        int byteoff = (prow * 128 + (mf * 16 + lg * 4) * 2) ^ ((prow & 7) << 4);
        *(uintx2*)((char*)ldsP + byteoff) = pk;
      }
    }

#pragma unroll
    for (int ks = 0; ks < 2; ++ks) {
      short8 pa[2];
#pragma unroll
      for (int qf = 0; qf < 2; ++qf) {
        int row = wq + qf * 16 + lr;
        int byteoff = (row * 128 + (ks * 4 + lg) * 16) ^ ((row & 7) << 4);
        pa[qf] = *(const short8*)((const char*)ldsP + byteoff);
      }
      short8 vf[8];
#pragma unroll
      for (int nf = 0; nf < 8; ++nf) {
        int row = nf * 16 + lr;
        vf[nf] = *(const short8*)&bVT[row * 64 + (((ks * 4 + lg) ^ (row & 7)) * 8)];
      }
      __builtin_amdgcn_s_setprio(1);
#pragma unroll
      for (int qf = 0; qf < 2; ++qf)
#pragma unroll
        for (int nf = 0; nf < 8; ++nf)
          oacc[qf][nf] =
              __builtin_amdgcn_mfma_f32_16x16x32_bf16(pa[qf], vf[nf], oacc[qf][nf], 0, 0, 0);
      __builtin_amdgcn_s_setprio(0);
    }
  };

#define SCHED_FENCE() __builtin_amdgcn_sched_barrier(0)
#define WAITBAR(N)                                                 \
  do {                                                             \
    SCHED_FENCE();                                                 \
    asm volatile("s_waitcnt vmcnt(" #N ")" ::: "memory");          \
    __builtin_amdgcn_s_barrier();                                  \
    SCHED_FENCE();                                                 \
  } while (0)
#define BAR()                                                      \
  do {                                                             \
    SCHED_FENCE();                                                 \
    __builtin_amdgcn_s_barrier();                                  \
    SCHED_FENCE();                                                 \
  } while (0)

  f32x4 wA[8], wB[8];
  WLOADP(wA);
  STAGE(0);

  for (int it = 0; it < 8; ++it) {
    {
      STAGE(1);
      WLOADP(wB);
      WAITBAR(16);
      tile_compute(&ldsK[0][0], &ldsVT[0][0], wA);
      BAR();
    }
    {
      if (it < 7) {
        STAGE(0);
        WLOADP(wA);
        WAITBAR(16);
      } else {
        WAITBAR(0);
      }
      tile_compute(&ldsK[1][0], &ldsVT[1][0], wB);
      if (it < 7) BAR();
    }
  }

  float lred[2];
#pragma unroll
  for (int nf = 0; nf < 2; ++nf) {
    float s = lacc[nf];
    s += __shfl_xor(s, 16);
    s += __shfl_xor(s, 32);
    lred[nf] = s;
  }

#pragma unroll
  for (int qf = 0; qf < 2; ++qf)
#pragma unroll
    for (int r = 0; r < 4; ++r) {
      float lv = __shfl(lred[qf], (lane & 48) | (lg * 4 + r));
      float linv = 1.0f / lv;
      int qrow = q0 + wq + qf * 16 + lg * 4 + r;
      size_t base = kvbase + (size_t)qrow * 512;
#pragma unroll
      for (int nf = 0; nf < 8; ++nf) {
        size_t idx = base + nf * 16 + lr;
        Ob[idx] = f2bf(bf2f(qb[idx]) + oacc[qf][nf][r] * linv);
      }
    }
#undef STAGE
#undef WLOADP
#undef WAITBAR
#undef BAR
#undef SCHED_FENCE
}

// ---------------- row LayerNorm over 512 cols (bf16 in, bf16 or f32 out) -----
template <bool F32OUT>
__global__ __launch_bounds__(256) void ln_kernel(const u16* __restrict__ in,
                                                 const float* __restrict__ g,
                                                 const float* __restrict__ be,
                                                 void* __restrict__ outp) {
  const int lane = threadIdx.x & 63, wid = threadIdx.x >> 6;
  const int row = blockIdx.x * 4 + wid;
  const u16* p = in + (size_t)row * 512 + lane * 8;
  short8 v = *(const short8*)p;
  float x[8];
  float s = 0.f, s2 = 0.f;
#pragma unroll
  for (int j = 0; j < 8; ++j) {
    x[j] = bf2f((u16)v[j]);
    s += x[j];
    s2 += x[j] * x[j];
  }
#pragma unroll
  for (int off = 1; off < 64; off <<= 1) {
    s += __shfl_xor(s, off);
    s2 += __shfl_xor(s2, off);
  }
  float mu = s * (1.f / 512.f);
  float var = s2 * (1.f / 512.f) - mu * mu;
  float rs = rsqrtf(var + 1e-5f);
  float4 ga = *(const float4*)(g + lane * 8);
  float4 gb = *(const float4*)(g + lane * 8 + 4);
  float4 ba = *(const float4*)(be + lane * 8);
  float4 bb = *(const float4*)(be + lane * 8 + 4);
  float gg[8] = {ga.x, ga.y, ga.z, ga.w, gb.x, gb.y, gb.z, gb.w};
  float bv[8] = {ba.x, ba.y, ba.z, ba.w, bb.x, bb.y, bb.z, bb.w};
  if constexpr (F32OUT) {
    float* out = (float*)outp + (size_t)row * 512 + lane * 8;
    float4 o0, o1;
    o0.x = (x[0] - mu) * rs * gg[0] + bv[0];
    o0.y = (x[1] - mu) * rs * gg[1] + bv[1];
    o0.z = (x[2] - mu) * rs * gg[2] + bv[2];
    o0.w = (x[3] - mu) * rs * gg[3] + bv[3];
    o1.x = (x[4] - mu) * rs * gg[4] + bv[4];
    o1.y = (x[5] - mu) * rs * gg[5] + bv[5];
    o1.z = (x[6] - mu) * rs * gg[6] + bv[6];
    o1.w = (x[7] - mu) * rs * gg[7] + bv[7];
    *(float4*)out = o0;
    *(float4*)(out + 4) = o1;
  } else {
    short8 o;
#pragma unroll
    for (int j = 0; j < 8; ++j) o[j] = (short)f2bf((x[j] - mu) * rs * gg[j] + bv[j]);
    *(short8*)((u16*)outp + (size_t)row * 512 + lane * 8) = o;
  }
}

extern "C" void kernel_launch(void* const* d_in, const int* in_sizes, int n_in,
                              void* d_out, int out_size, void* d_ws, size_t ws_size,
                              hipStream_t stream) {
  (void)in_sizes; (void)n_in; (void)out_size; (void)ws_size;
  const float* Q   = (const float*)d_in[0];
  const float* K   = (const float*)d_in[1];
  const float* Wt  = (const float*)d_in[2];
  const float* Wq  = (const float*)d_in[3];
  const float* bq  = (const float*)d_in[4];
  const float* Wk  = (const float*)d_in[5];
  const float* bk  = (const float*)d_in[6];
  const float* Wv  = (const float*)d_in[7];
  const float* bv  = (const float*)d_in[8];
  const float* Wo  = (const float*)d_in[9];
  const float* bo  = (const float*)d_in[10];
  const float* g0  = (const float*)d_in[11];
  const float* be0 = (const float*)d_in[12];
  const float* g1  = (const float*)d_in[13];
  const float* be1 = (const float*)d_in[14];

  char* ws = (char*)d_ws;
  const size_t MB16 = 16777216;
  u16* qb  = (u16*)(ws);
  u16* kb  = (u16*)(ws + MB16);
  u16* vbT = (u16*)(ws + 2 * MB16);  // V^T per head [64][128][1024]
  u16* Wb  = (u16*)(ws + 3 * MB16);
  u16* Ob  = (u16*)d_out;

  cvt_w_kernel<<<dim3(256, 4), 256, 0, stream>>>(Wq, Wk, Wv, Wo, Wb);
  gemm3_kernel<<<dim3(4, 128, 3), 256, 0, stream>>>(Q, K, Wb, bq, bk, bv, qb, kb, vbT);
  attn_kernel<<<dim3(512), 256, 0, stream>>>(qb, kb, vbT, Wt, Ob);
  ln_kernel<false><<<4096, 256, 0, stream>>>(Ob, g0, be0, qb);
  gemmo_kernel<<<dim3(4, 128), 256, 0, stream>>>(qb, Wb + 786432, bo, kb);
  ln_kernel<true><<<4096, 256, 0, stream>>>(kb, g1, be1, d_out);
}

// Round 12
// 267.323 us; speedup vs baseline: 1.0024x; 1.0024x over previous
//
#include <hip/hip_runtime.h>

typedef unsigned short u16;
typedef unsigned int u32;
typedef __attribute__((ext_vector_type(8))) short short8;
typedef __attribute__((ext_vector_type(4))) float f32x4;
typedef __attribute__((ext_vector_type(2))) u32 uintx2;
typedef __attribute__((address_space(3))) u32 lds32;
typedef const __attribute__((address_space(1))) u32 g32c;

__device__ __forceinline__ u16 f2bf(float f) {
  union { float f; u32 u; } v; v.f = f;
  return (u16)((v.u + 0x7fffu + ((v.u >> 16) & 1u)) >> 16);  // RNE
}
__device__ __forceinline__ float bf2f(u16 h) {
  union { u32 u; float f; } v; v.u = ((u32)h) << 16;
  return v.f;
}

// ---------------- weight convert: 4x [512x512] f32 -> bf16 ----------------
__global__ void cvt_w_kernel(const float* __restrict__ Wq, const float* __restrict__ Wk,
                             const float* __restrict__ Wv, const float* __restrict__ Wo,
                             u16* __restrict__ dst) {
  int m = blockIdx.y;
  const float* s = (m == 0) ? Wq : (m == 1) ? Wk : (m == 2) ? Wv : Wo;
  int idx = (blockIdx.x * 256 + threadIdx.x) * 4;
  float4 v = *(const float4*)(s + idx);
  uintx2 pk;
  pk[0] = (u32)f2bf(v.x) | ((u32)f2bf(v.y) << 16);
  pk[1] = (u32)f2bf(v.z) | ((u32)f2bf(v.w) << 16);
  *(uintx2*)(dst + m * 262144 + idx) = pk;
}

// ---------------- BT GEMM body (round-6/9 proven): C = A B^T ----------------
template <bool AF32, bool OUTMODE, bool TRANSV>
__device__ __forceinline__ void gemm_bt_body(const void* __restrict__ Ap,
                                             const u16* __restrict__ Bw,
                                             const float* __restrict__ bias,
                                             u16* __restrict__ C) {
  __shared__ u16 ldsA[128 * 64];
  __shared__ u16 ldsB[128 * 64];
  const int t = threadIdx.x;
  const int lane = t & 63, wid = t >> 6;
  const int lr = lane & 15, lg = lane >> 4;
  const int n0 = blockIdx.x * 128;
  const int m0 = blockIdx.y * 128;
  const int wr = (wid >> 1) * 64, wc = (wid & 1) * 64;

  f32x4 acc[4][4];
#pragma unroll
  for (int i = 0; i < 4; ++i)
#pragma unroll
    for (int j = 0; j < 4; ++j)
#pragma unroll
      for (int r = 0; r < 4; ++r) acc[i][j][r] = 0.f;

  for (int kt = 0; kt < 512; kt += 64) {
    __syncthreads();
#pragma unroll
    for (int i = 0; i < 4; ++i) {
      int lin = i * 256 + t;
      int row = lin >> 3, u = lin & 7;
      int pu = u ^ (row & 7);
      if constexpr (AF32) {
        const float* src = (const float*)Ap + (size_t)(m0 + row) * 512 + kt + u * 8;
        float4 v0 = *(const float4*)src;
        float4 v1 = *(const float4*)(src + 4);
        short8 pk;
        pk[0] = (short)f2bf(v0.x); pk[1] = (short)f2bf(v0.y);
        pk[2] = (short)f2bf(v0.z); pk[3] = (short)f2bf(v0.w);
        pk[4] = (short)f2bf(v1.x); pk[5] = (short)f2bf(v1.y);
        pk[6] = (short)f2bf(v1.z); pk[7] = (short)f2bf(v1.w);
        *(short8*)&ldsA[row * 64 + pu * 8] = pk;
      } else {
        const u16* src = (const u16*)Ap + (size_t)(m0 + row) * 512 + kt + u * 8;
        *(short8*)&ldsA[row * 64 + pu * 8] = *(const short8*)src;
      }
      const u16* bsrc = Bw + (size_t)(n0 + row) * 512 + kt + u * 8;
      *(short8*)&ldsB[row * 64 + pu * 8] = *(const short8*)bsrc;
    }
    __syncthreads();
#pragma unroll
    for (int kk = 0; kk < 2; ++kk) {
      short8 af[4], bfr[4];
#pragma unroll
      for (int mf = 0; mf < 4; ++mf) {
        int row = wr + mf * 16 + lr;
        af[mf] = *(const short8*)&ldsA[row * 64 + (((kk * 4 + lg) ^ (row & 7)) * 8)];
      }
#pragma unroll
      for (int nf = 0; nf < 4; ++nf) {
        int row = wc + nf * 16 + lr;
        bfr[nf] = *(const short8*)&ldsB[row * 64 + (((kk * 4 + lg) ^ (row & 7)) * 8)];
      }
#pragma unroll
      for (int mf = 0; mf < 4; ++mf)
#pragma unroll
        for (int nf = 0; nf < 4; ++nf)
          acc[mf][nf] =
              __builtin_amdgcn_mfma_f32_16x16x32_bf16(af[mf], bfr[nf], acc[mf][nf], 0, 0, 0);
    }
  }

  if constexpr (TRANSV) {
    const int h_ = n0 >> 7;
#pragma unroll
    for (int mf = 0; mf < 4; ++mf)
#pragma unroll
      for (int nf = 0; nf < 4; ++nf) {
        int d = wc + nf * 16 + lr;
        int rr0 = m0 + wr + mf * 16 + lg * 4;
        int b_ = rr0 >> 10;
        int k0 = rr0 & 1023;
        float bvv = bias[n0 + d];
        uintx2 pk;
        pk[0] = (u32)f2bf(acc[mf][nf][0] + bvv) | ((u32)f2bf(acc[mf][nf][1] + bvv) << 16);
        pk[1] = (u32)f2bf(acc[mf][nf][2] + bvv) | ((u32)f2bf(acc[mf][nf][3] + bvv) << 16);
        *(uintx2*)(C + (((size_t)b_ * 4 + h_) * 128 + d) * 1024 + k0) = pk;
      }
  } else {
#pragma unroll
    for (int mf = 0; mf < 4; ++mf)
#pragma unroll
      for (int nf = 0; nf < 4; ++nf) {
        int c = n0 + wc + nf * 16 + lr;
        float bv = bias[c];
#pragma unroll
        for (int r = 0; r < 4; ++r) {
          int rr = m0 + wr + mf * 16 + lg * 4 + r;  // C/D: col=lane&15, row=(lane>>4)*4+reg
          float v = acc[mf][nf][r] + bv;
          if constexpr (OUTMODE) {
            v = v > 0.f ? v : 0.f;
            v += bf2f(((const u16*)Ap)[(size_t)rr * 512 + c]);
          }
          C[(size_t)rr * 512 + c] = f2bf(v);
        }
      }
  }
}

// ---- fused K/V projection: stage A(=K, f32->bf16) ONCE, two B tiles, two accs ----
__device__ __forceinline__ void gemm_kv_body(const float* __restrict__ Ap,
                                             const u16* __restrict__ Bk,
                                             const u16* __restrict__ Bv,
                                             const float* __restrict__ biask,
                                             const float* __restrict__ biasv,
                                             u16* __restrict__ Ck, u16* __restrict__ CvT) {
  __shared__ u16 ldsA[128 * 64];
  __shared__ u16 ldsBk[128 * 64];
  __shared__ u16 ldsBv[128 * 64];
  const int t = threadIdx.x;
  const int lane = t & 63, wid = t >> 6;
  const int lr = lane & 15, lg = lane >> 4;
  const int n0 = blockIdx.x * 128;
  const int m0 = blockIdx.y * 128;
  const int wr = (wid >> 1) * 64, wc = (wid & 1) * 64;

  f32x4 accK[4][4], accV[4][4];
#pragma unroll
  for (int i = 0; i < 4; ++i)
#pragma unroll
    for (int j = 0; j < 4; ++j)
#pragma unroll
      for (int r = 0; r < 4; ++r) { accK[i][j][r] = 0.f; accV[i][j][r] = 0.f; }

  for (int kt = 0; kt < 512; kt += 64) {
    __syncthreads();
#pragma unroll
    for (int i = 0; i < 4; ++i) {
      int lin = i * 256 + t;
      int row = lin >> 3, u = lin & 7;
      int pu = u ^ (row & 7);
      const float* src = Ap + (size_t)(m0 + row) * 512 + kt + u * 8;
      float4 v0 = *(const float4*)src;
      float4 v1 = *(const float4*)(src + 4);
      short8 pk;
      pk[0] = (short)f2bf(v0.x); pk[1] = (short)f2bf(v0.y);
      pk[2] = (short)f2bf(v0.z); pk[3] = (short)f2bf(v0.w);
      pk[4] = (short)f2bf(v1.x); pk[5] = (short)f2bf(v1.y);
      pk[6] = (short)f2bf(v1.z); pk[7] = (short)f2bf(v1.w);
      *(short8*)&ldsA[row * 64 + pu * 8] = pk;
      *(short8*)&ldsBk[row * 64 + pu * 8] =
          *(const short8*)(Bk + (size_t)(n0 + row) * 512 + kt + u * 8);
      *(short8*)&ldsBv[row * 64 + pu * 8] =
          *(const short8*)(Bv + (size_t)(n0 + row) * 512 + kt + u * 8);
    }
    __syncthreads();
#pragma unroll
    for (int kk = 0; kk < 2; ++kk) {
      short8 af[4];
#pragma unroll
      for (int mf = 0; mf < 4; ++mf) {
        int row = wr + mf * 16 + lr;
        af[mf] = *(const short8*)&ldsA[row * 64 + (((kk * 4 + lg) ^ (row & 7)) * 8)];
      }
      {  // K-proj MFMAs
        short8 bfr[4];
#pragma unroll
        for (int nf = 0; nf < 4; ++nf) {
          int row = wc + nf * 16 + lr;
          bfr[nf] = *(const short8*)&ldsBk[row * 64 + (((kk * 4 + lg) ^ (row & 7)) * 8)];
        }
#pragma unroll
        for (int mf = 0; mf < 4; ++mf)
#pragma unroll
          for (int nf = 0; nf < 4; ++nf)
            accK[mf][nf] =
                __builtin_amdgcn_mfma_f32_16x16x32_bf16(af[mf], bfr[nf], accK[mf][nf], 0, 0, 0);
      }
      {  // V-proj MFMAs (same A fragments)
        short8 bfr[4];
#pragma unroll
        for (int nf = 0; nf < 4; ++nf) {
          int row = wc + nf * 16 + lr;
          bfr[nf] = *(const short8*)&ldsBv[row * 64 + (((kk * 4 + lg) ^ (row & 7)) * 8)];
        }
#pragma unroll
        for (int mf = 0; mf < 4; ++mf)
#pragma unroll
          for (int nf = 0; nf < 4; ++nf)
            accV[mf][nf] =
                __builtin_amdgcn_mfma_f32_16x16x32_bf16(af[mf], bfr[nf], accV[mf][nf], 0, 0, 0);
      }
    }
  }

  // epilogue 1: kb normal layout
#pragma unroll
  for (int mf = 0; mf < 4; ++mf)
#pragma unroll
    for (int nf = 0; nf < 4; ++nf) {
      int c = n0 + wc + nf * 16 + lr;
      float bv = biask[c];
#pragma unroll
      for (int r = 0; r < 4; ++r) {
        int rr = m0 + wr + mf * 16 + lg * 4 + r;
        Ck[(size_t)rr * 512 + c] = f2bf(accK[mf][nf][r] + bv);
      }
    }
  // epilogue 2: vbT transposed-per-head layout
  {
    const int h_ = n0 >> 7;
#pragma unroll
    for (int mf = 0; mf < 4; ++mf)
#pragma unroll
      for (int nf = 0; nf < 4; ++nf) {
        int d = wc + nf * 16 + lr;
        int rr0 = m0 + wr + mf * 16 + lg * 4;
        int b_ = rr0 >> 10;
        int k0 = rr0 & 1023;
        float bvv = biasv[n0 + d];
        uintx2 pk;
        pk[0] = (u32)f2bf(accV[mf][nf][0] + bvv) | ((u32)f2bf(accV[mf][nf][1] + bvv) << 16);
        pk[1] = (u32)f2bf(accV[mf][nf][2] + bvv) | ((u32)f2bf(accV[mf][nf][3] + bvv) << 16);
        *(uintx2*)(CvT + (((size_t)b_ * 4 + h_) * 128 + d) * 1024 + k0) = pk;
      }
  }
}

// z=0: Q projection; z=1: fused K+V projections
__global__ __launch_bounds__(256) void gemm3_kernel(const float* __restrict__ Q,
                                                    const float* __restrict__ K,
                                                    const u16* __restrict__ Wb,
                                                    const float* __restrict__ bq,
                                                    const float* __restrict__ bk,
                                                    const float* __restrict__ bv,
                                                    u16* qb, u16* kb, u16* vbT) {
  if (blockIdx.z == 0) {
    gemm_bt_body<true, false, false>(Q, Wb, bq, qb);
  } else {
    gemm_kv_body(K, Wb + 262144, Wb + 524288, bk, bv, kb, vbT);
  }
}

__global__ __launch_bounds__(256) void gemmo_kernel(const u16* __restrict__ X,
                                                    const u16* __restrict__ Wb,
                                                    const float* __restrict__ bo,
                                                    u16* Z) {
  gemm_bt_body<false, true, false>(X, Wb, bo, Z);
}

// ---------------- fused attention (round-9, frozen) ----------------
__global__ __launch_bounds__(256) void attn_kernel(const u16* __restrict__ qb,
                                                   const u16* __restrict__ kb,
                                                   const u16* __restrict__ vbT,
                                                   const float* __restrict__ Wt,
                                                   u16* __restrict__ Ob) {
  __shared__ __align__(16) u16 ldsK[2][64 * 128];
  __shared__ __align__(16) u16 ldsVT[2][128 * 64];
  __shared__ __align__(16) u16 ldsP[128 * 64];
  const int t = threadIdx.x;
  const int lane = t & 63, wid = t >> 6;
  const int lr = lane & 15, lg = lane >> 4;
  const int bid = blockIdx.x;
  const int x_ = bid & 7, s_ = bid >> 3;
  const int hb = ((s_ & 7) << 3) | x_;  // h*16 + b
  const int q0 = (s_ >> 3) * 128;
  const int b = hb & 15;
  const int h = hb >> 4;
  const int wq = wid * 32;
  const size_t kvbase = ((size_t)b * 1024) * 512 + h * 128;
  const size_t vtbase = ((size_t)b * 4 + h) * 131072;  // V^T [128 d][1024 k]
  const float SCALE = 0.044194173824159216f;           // 1/sqrt(512)

  const u16* ksrc[4];
  const u16* vtsrc[4];
#pragma unroll
  for (int i = 0; i < 4; ++i) {
    {
      int lin = i * 256 + t;
      int row = lin >> 4, u = lin & 15;
      ksrc[i] = kb + kvbase + (size_t)row * 512 + ((u ^ (row & 15)) * 8);
    }
    {
      int lin = i * 256 + t;
      int row = lin >> 3, u = lin & 7;
      vtsrc[i] = vbT + vtbase + (size_t)row * 1024 + ((u ^ (row & 7)) * 8);
    }
  }
  const int wslot = (t & 192) * 8;

#define STAGE(bu)                                                                           \
  do {                                                                                      \
    _Pragma("unroll") for (int i_ = 0; i_ < 4; ++i_) {                                      \
      __builtin_amdgcn_global_load_lds((g32c*)(ksrc[i_]),                                   \
                                       (lds32*)(&ldsK[bu][i_ * 2048 + wslot]), 16, 0, 0);   \
      __builtin_amdgcn_global_load_lds((g32c*)(vtsrc[i_]),                                  \
                                       (lds32*)(&ldsVT[bu][i_ * 2048 + wslot]), 16, 0, 0);  \
      ksrc[i_] += 32768;                                                                    \
      vtsrc[i_] += 64;                                                                      \
    }                                                                                       \
  } while (0)

  const float* wp0 = Wt + ((size_t)hb * 1024 + q0 + wq + lr) * 1024 + lg * 4;
  const float* wp1 = wp0 + 16 * 1024;

#define WLOADP(W)                                          \
  do {                                                     \
    _Pragma("unroll") for (int j_ = 0; j_ < 4; ++j_) {     \
      W[j_]     = *(const f32x4*)(wp0 + j_ * 16);          \
      W[4 + j_] = *(const f32x4*)(wp1 + j_ * 16);          \
    }                                                      \
    wp0 += 64; wp1 += 64;                                  \
  } while (0)

  short8 qfr[2][4];
#pragma unroll
  for (int nf = 0; nf < 2; ++nf) {
    const u16* qp = qb + kvbase + (size_t)(q0 + wq + nf * 16 + lr) * 512 + lg * 8;
#pragma unroll
    for (int ds = 0; ds < 4; ++ds) qfr[nf][ds] = *(const short8*)(qp + ds * 32);
  }

  f32x4 oacc[2][8];
#pragma unroll
  for (int i = 0; i < 2; ++i)
#pragma unroll
    for (int j = 0; j < 8; ++j)
#pragma unroll
      for (int r = 0; r < 4; ++r) oacc[i][j][r] = 0.f;
  float lacc[2] = {0.f, 0.f};

  auto tile_compute = [&](const u16* bK, const u16* bVT, const f32x4 (&W)[8]) {
    f32x4 sacc[4][2];
#pragma unroll
    for (int i = 0; i < 4; ++i)
#pragma unroll
      for (int j = 0; j < 2; ++j)
#pragma unroll
        for (int r = 0; r < 4; ++r) sacc[i][j][r] = 0.f;

#pragma unroll
    for (int ds = 0; ds < 4; ++ds) {
      short8 kf[4];
#pragma unroll
      for (int mf = 0; mf < 4; ++mf) {
        int row = mf * 16 + lr;
        kf[mf] = *(const short8*)&bK[row * 128 + (((ds * 4 + lg) ^ (row & 15)) * 8)];
      }
      __builtin_amdgcn_s_setprio(1);
#pragma unroll
      for (int mf = 0; mf < 4; ++mf)
#pragma unroll
        for (int nf = 0; nf < 2; ++nf)
          sacc[mf][nf] =
              __builtin_amdgcn_mfma_f32_16x16x32_bf16(kf[mf], qfr[nf][ds], sacc[mf][nf], 0, 0, 0);
      __builtin_amdgcn_s_setprio(0);
    }

#pragma unroll
    for (int nf = 0; nf < 2; ++nf) {
      int prow = wq + nf * 16 + lr;
#pragma unroll
      for (int mf = 0; mf < 4; ++mf) {
        f32x4 w4 = W[nf * 4 + mf];
        float p0 = w4[0] * __expf(sacc[mf][nf][0] * SCALE);
        float p1 = w4[1] * __expf(sacc[mf][nf][1] * SCALE);
        float p2 = w4[2] * __expf(sacc[mf][nf][2] * SCALE);
        float p3 = w4[3] * __expf(sacc[mf][nf][3] * SCALE);
        lacc[nf] += (p0 + p1) + (p2 + p3);
        uintx2 pk;
        pk[0] = (u32)f2bf(p0) | ((u32)f2bf(p1) << 16);
        pk[1] = (u32)f2bf(p2) | ((u32)f2bf(p3) << 16);
        int byteoff = (prow * 128 + (mf * 16 + lg * 4) * 2) ^ ((prow & 7) << 4);
        *(uintx2*)((char*)ldsP + byteoff) = pk;
      }
    }

#pragma unroll
    for (int ks = 0; ks < 2; ++ks) {
      short8 pa[2];
#pragma unroll
      for (int qf = 0; qf < 2; ++qf) {
        int row = wq + qf * 16 + lr;
        int byteoff = (row * 128 + (ks * 4 + lg) * 16) ^ ((row & 7) << 4);
        pa[qf] = *(const short8*)((const char*)ldsP + byteoff);
      }
      short8 vf[8];
#pragma unroll
      for (int nf = 0; nf < 8; ++nf) {
        int row = nf * 16 + lr;
        vf[nf] = *(const short8*)&bVT[row * 64 + (((ks * 4 + lg) ^ (row & 7)) * 8)];
      }
      __builtin_amdgcn_s_setprio(1);
#pragma unroll
      for (int qf = 0; qf < 2; ++qf)
#pragma unroll
        for (int nf = 0; nf < 8; ++nf)
          oacc[qf][nf] =
              __builtin_amdgcn_mfma_f32_16x16x32_bf16(pa[qf], vf[nf], oacc[qf][nf], 0, 0, 0);
      __builtin_amdgcn_s_setprio(0);
    }
  };

#define SCHED_FENCE() __builtin_amdgcn_sched_barrier(0)
#define WAITBAR(N)                                                 \
  do {                                                             \
    SCHED_FENCE();                                                 \
    asm volatile("s_waitcnt vmcnt(" #N ")" ::: "memory");          \
    __builtin_amdgcn_s_barrier();                                  \
    SCHED_FENCE();                                                 \
  } while (0)
#define BAR()                                                      \
  do {                                                             \
    SCHED_FENCE();                                                 \
    __builtin_amdgcn_s_barrier();                                  \
    SCHED_FENCE();                                                 \
  } while (0)

  f32x4 wA[8], wB[8];
  WLOADP(wA);
  STAGE(0);

  for (int it = 0; it < 8; ++it) {
    {
      STAGE(1);
      WLOADP(wB);
      WAITBAR(16);
      tile_compute(&ldsK[0][0], &ldsVT[0][0], wA);
      BAR();
    }
    {
      if (it < 7) {
        STAGE(0);
        WLOADP(wA);
        WAITBAR(16);
      } else {
        WAITBAR(0);
      }
      tile_compute(&ldsK[1][0], &ldsVT[1][0], wB);
      if (it < 7) BAR();
    }
  }

  float lred[2];
#pragma unroll
  for (int nf = 0; nf < 2; ++nf) {
    float s = lacc[nf];
    s += __shfl_xor(s, 16);
    s += __shfl_xor(s, 32);
    lred[nf] = s;
  }

#pragma unroll
  for (int qf = 0; qf < 2; ++qf)
#pragma unroll
    for (int r = 0; r < 4; ++r) {
      float lv = __shfl(lred[qf], (lane & 48) | (lg * 4 + r));
      float linv = 1.0f / lv;
      int qrow = q0 + wq + qf * 16 + lg * 4 + r;
      size_t base = kvbase + (size_t)qrow * 512;
#pragma unroll
      for (int nf = 0; nf < 8; ++nf) {
        size_t idx = base + nf * 16 + lr;
        Ob[idx] = f2bf(bf2f(qb[idx]) + oacc[qf][nf][r] * linv);
      }
    }
#undef STAGE
#undef WLOADP
#undef WAITBAR
#undef BAR
#undef SCHED_FENCE
}

// ---------------- row LayerNorm over 512 cols (bf16 in, bf16 or f32 out) -----
template <bool F32OUT>
__global__ __launch_bounds__(256) void ln_kernel(const u16* __restrict__ in,
                                                 const float* __restrict__ g,
                                                 const float* __restrict__ be,
                                                 void* __restrict__ outp) {
  const int lane = threadIdx.x & 63, wid = threadIdx.x >> 6;
  const int row = blockIdx.x * 4 + wid;
  const u16* p = in + (size_t)row * 512 + lane * 8;
  short8 v = *(const short8*)p;
  float x[8];
  float s = 0.f, s2 = 0.f;
#pragma unroll
  for (int j = 0; j < 8; ++j) {
    x[j] = bf2f((u16)v[j]);
    s += x[j];
    s2 += x[j] * x[j];
  }
#pragma unroll
  for (int off = 1; off < 64; off <<= 1) {
    s += __shfl_xor(s, off);
    s2 += __shfl_xor(s2, off);
  }
  float mu = s * (1.f / 512.f);
  float var = s2 * (1.f / 512.f) - mu * mu;
  float rs = rsqrtf(var + 1e-5f);
  float4 ga = *(const float4*)(g + lane * 8);
  float4 gb = *(const float4*)(g + lane * 8 + 4);
  float4 ba = *(const float4*)(be + lane * 8);
  float4 bb = *(const float4*)(be + lane * 8 + 4);
  float gg[8] = {ga.x, ga.y, ga.z, ga.w, gb.x, gb.y, gb.z, gb.w};
  float bv[8] = {ba.x, ba.y, ba.z, ba.w, bb.x, bb.y, bb.z, bb.w};
  if constexpr (F32OUT) {
    float* out = (float*)outp + (size_t)row * 512 + lane * 8;
    float4 o0, o1;
    o0.x = (x[0] - mu) * rs * gg[0] + bv[0];
    o0.y = (x[1] - mu) * rs * gg[1] + bv[1];
    o0.z = (x[2] - mu) * rs * gg[2] + bv[2];
    o0.w = (x[3] - mu) * rs * gg[3] + bv[3];
    o1.x = (x[4] - mu) * rs * gg[4] + bv[4];
    o1.y = (x[5] - mu) * rs * gg[5] + bv[5];
    o1.z = (x[6] - mu) * rs * gg[6] + bv[6];
    o1.w = (x[7] - mu) * rs * gg[7] + bv[7];
    *(float4*)out = o0;
    *(float4*)(out + 4) = o1;
  } else {
    short8 o;
#pragma unroll
    for (int j = 0; j < 8; ++j) o[j] = (short)f2bf((x[j] - mu) * rs * gg[j] + bv[j]);
    *(short8*)((u16*)outp + (size_t)row * 512 + lane * 8) = o;
  }
}

extern "C" void kernel_launch(void* const* d_in, const int* in_sizes, int n_in,
                              void* d_out, int out_size, void* d_ws, size_t ws_size,
                              hipStream_t stream) {
  (void)in_sizes; (void)n_in; (void)out_size; (void)ws_size;
  const float* Q   = (const float*)d_in[0];
  const float* K   = (const float*)d_in[1];
  const float* Wt  = (const float*)d_in[2];
  const float* Wq  = (const float*)d_in[3];
  const float* bq  = (const float*)d_in[4];
  const float* Wk  = (const float*)d_in[5];
  const float* bk  = (const float*)d_in[6];
  const float* Wv  = (const float*)d_in[7];
  const float* bv  = (const float*)d_in[8];
  const float* Wo  = (const float*)d_in[9];
  const float* bo  = (const float*)d_in[10];
  const float* g0  = (const float*)d_in[11];
  const float* be0 = (const float*)d_in[12];
  const float* g1  = (const float*)d_in[13];
  const float* be1 = (const float*)d_in[14];

  char* ws = (char*)d_ws;
  const size_t MB16 = 16777216;
  u16* qb  = (u16*)(ws);
  u16* kb  = (u16*)(ws + MB16);
  u16* vbT = (u16*)(ws + 2 * MB16);  // V^T per head [64][128][1024]
  u16* Wb  = (u16*)(ws + 3 * MB16);
  u16* Ob  = (u16*)d_out;

  cvt_w_kernel<<<dim3(256, 4), 256, 0, stream>>>(Wq, Wk, Wv, Wo, Wb);
  gemm3_kernel<<<dim3(4, 128, 2), 256, 0, stream>>>(Q, K, Wb, bq, bk, bv, qb, kb, vbT);
  attn_kernel<<<dim3(512), 256, 0, stream>>>(qb, kb, vbT, Wt, Ob);
  ln_kernel<false><<<4096, 256, 0, stream>>>(Ob, g0, be0, qb);
  gemmo_kernel<<<dim3(4, 128), 256, 0, stream>>>(qb, Wb + 786432, bo, kb);
  ln_kernel<true><<<4096, 256, 0, stream>>>(kb, g1, be1, d_out);
}

// Round 13
// 248.871 us; speedup vs baseline: 1.0767x; 1.0741x over previous
//
#include <hip/hip_runtime.h>

typedef unsigned short u16;
typedef unsigned int u32;
typedef __attribute__((ext_vector_type(8))) short short8;
typedef __attribute__((ext_vector_type(4))) float f32x4;
typedef __attribute__((ext_vector_type(2))) u32 uintx2;
typedef __attribute__((address_space(3))) u32 lds32;
typedef const __attribute__((address_space(1))) u32 g32c;

__device__ __forceinline__ u16 f2bf(float f) {
  union { float f; u32 u; } v; v.f = f;
  return (u16)((v.u + 0x7fffu + ((v.u >> 16) & 1u)) >> 16);  // RNE
}
__device__ __forceinline__ float bf2f(u16 h) {
  union { u32 u; float f; } v; v.u = ((u32)h) << 16;
  return v.f;
}

// ---------------- weight convert: 4x [512x512] f32 -> bf16 ----------------
__global__ void cvt_w_kernel(const float* __restrict__ Wq, const float* __restrict__ Wk,
                             const float* __restrict__ Wv, const float* __restrict__ Wo,
                             u16* __restrict__ dst) {
  int m = blockIdx.y;
  const float* s = (m == 0) ? Wq : (m == 1) ? Wk : (m == 2) ? Wv : Wo;
  int idx = (blockIdx.x * 256 + threadIdx.x) * 4;
  float4 v = *(const float4*)(s + idx);
  uintx2 pk;
  pk[0] = (u32)f2bf(v.x) | ((u32)f2bf(v.y) << 16);
  pk[1] = (u32)f2bf(v.z) | ((u32)f2bf(v.w) << 16);
  *(uintx2*)(dst + m * 262144 + idx) = pk;
}

// ---------------- BT GEMM body: C[m,n] = sum_k A[m,k]*B[n,k] ----------------
// TRANSV: write output transposed per head: C_t[(b*4+h)*128 + d][k]
template <bool AF32, bool OUTMODE, bool TRANSV>
__device__ __forceinline__ void gemm_bt_body(const void* __restrict__ Ap,
                                             const u16* __restrict__ Bw,
                                             const float* __restrict__ bias,
                                             u16* __restrict__ C) {
  __shared__ u16 ldsA[128 * 64];
  __shared__ u16 ldsB[128 * 64];
  const int t = threadIdx.x;
  const int lane = t & 63, wid = t >> 6;
  const int lr = lane & 15, lg = lane >> 4;
  const int n0 = blockIdx.x * 128;
  const int m0 = blockIdx.y * 128;
  const int wr = (wid >> 1) * 64, wc = (wid & 1) * 64;

  f32x4 acc[4][4];
#pragma unroll
  for (int i = 0; i < 4; ++i)
#pragma unroll
    for (int j = 0; j < 4; ++j)
#pragma unroll
      for (int r = 0; r < 4; ++r) acc[i][j][r] = 0.f;

  for (int kt = 0; kt < 512; kt += 64) {
    __syncthreads();
#pragma unroll
    for (int i = 0; i < 4; ++i) {
      int lin = i * 256 + t;
      int row = lin >> 3, u = lin & 7;
      int pu = u ^ (row & 7);
      if constexpr (AF32) {
        const float* src = (const float*)Ap + (size_t)(m0 + row) * 512 + kt + u * 8;
        float4 v0 = *(const float4*)src;
        float4 v1 = *(const float4*)(src + 4);
        short8 pk;
        pk[0] = (short)f2bf(v0.x); pk[1] = (short)f2bf(v0.y);
        pk[2] = (short)f2bf(v0.z); pk[3] = (short)f2bf(v0.w);
        pk[4] = (short)f2bf(v1.x); pk[5] = (short)f2bf(v1.y);
        pk[6] = (short)f2bf(v1.z); pk[7] = (short)f2bf(v1.w);
        *(short8*)&ldsA[row * 64 + pu * 8] = pk;
      } else {
        const u16* src = (const u16*)Ap + (size_t)(m0 + row) * 512 + kt + u * 8;
        *(short8*)&ldsA[row * 64 + pu * 8] = *(const short8*)src;
      }
      const u16* bsrc = Bw + (size_t)(n0 + row) * 512 + kt + u * 8;
      *(short8*)&ldsB[row * 64 + pu * 8] = *(const short8*)bsrc;
    }
    __syncthreads();
#pragma unroll
    for (int kk = 0; kk < 2; ++kk) {
      short8 af[4], bfr[4];
#pragma unroll
      for (int mf = 0; mf < 4; ++mf) {
        int row = wr + mf * 16 + lr;
        af[mf] = *(const short8*)&ldsA[row * 64 + (((kk * 4 + lg) ^ (row & 7)) * 8)];
      }
#pragma unroll
      for (int nf = 0; nf < 4; ++nf) {
        int row = wc + nf * 16 + lr;
        bfr[nf] = *(const short8*)&ldsB[row * 64 + (((kk * 4 + lg) ^ (row & 7)) * 8)];
      }
#pragma unroll
      for (int mf = 0; mf < 4; ++mf)
#pragma unroll
        for (int nf = 0; nf < 4; ++nf)
          acc[mf][nf] =
              __builtin_amdgcn_mfma_f32_16x16x32_bf16(af[mf], bfr[nf], acc[mf][nf], 0, 0, 0);
    }
  }

  if constexpr (TRANSV) {
    const int h_ = n0 >> 7;
#pragma unroll
    for (int mf = 0; mf < 4; ++mf)
#pragma unroll
      for (int nf = 0; nf < 4; ++nf) {
        int d = wc + nf * 16 + lr;
        int rr0 = m0 + wr + mf * 16 + lg * 4;
        int b_ = rr0 >> 10;
        int k0 = rr0 & 1023;
        float bvv = bias[n0 + d];
        uintx2 pk;
        pk[0] = (u32)f2bf(acc[mf][nf][0] + bvv) | ((u32)f2bf(acc[mf][nf][1] + bvv) << 16);
        pk[1] = (u32)f2bf(acc[mf][nf][2] + bvv) | ((u32)f2bf(acc[mf][nf][3] + bvv) << 16);
        *(uintx2*)(C + (((size_t)b_ * 4 + h_) * 128 + d) * 1024 + k0) = pk;
      }
  } else {
#pragma unroll
    for (int mf = 0; mf < 4; ++mf)
#pragma unroll
      for (int nf = 0; nf < 4; ++nf) {
        int c = n0 + wc + nf * 16 + lr;
        float bv = bias[c];
#pragma unroll
        for (int r = 0; r < 4; ++r) {
          int rr = m0 + wr + mf * 16 + lg * 4 + r;
          float v = acc[mf][nf][r] + bv;
          if constexpr (OUTMODE) {
            v = v > 0.f ? v : 0.f;
            v += bf2f(((const u16*)Ap)[(size_t)rr * 512 + c]);
          }
          C[(size_t)rr * 512 + c] = f2bf(v);
        }
      }
  }
}

// fused Q/K/V projections in one launch (z selects); V written transposed per head
__global__ __launch_bounds__(256) void gemm3_kernel(const float* __restrict__ Q,
                                                    const float* __restrict__ K,
                                                    const u16* __restrict__ Wb,
                                                    const float* __restrict__ bq,
                                                    const float* __restrict__ bk,
                                                    const float* __restrict__ bv,
                                                    u16* qb, u16* kb, u16* vbT) {
  int z = blockIdx.z;
  if (z == 2) {
    gemm_bt_body<true, false, true>(K, Wb + 524288, bv, vbT);
  } else {
    const void* Ap = (z == 0) ? (const void*)Q : (const void*)K;
    const u16* Bw = Wb + z * 262144;
    const float* bias = (z == 0) ? bq : bk;
    u16* C = (z == 0) ? qb : kb;
    gemm_bt_body<true, false, false>(Ap, Bw, bias, C);
  }
}

__global__ __launch_bounds__(256) void gemmo_kernel(const u16* __restrict__ X,
                                                    const u16* __restrict__ Wb,
                                                    const float* __restrict__ bo,
                                                    u16* Z) {
  gemm_bt_body<false, true, false>(X, Wb, bo, Z);
}

// ---------------- fused attention, async-pipelined (round-6, best-known) ----
// 4 waves x 32 q (q-tile 128). KVBLK=64, K and V^T double-buffered in LDS via
// global_load_lds (pre-swizzled global source, linear LDS dest). Wt prior
// prefetched one tile ahead into named reg sets wA/wB. Counted vmcnt(16) +
// raw s_barrier; barrier after every compute protects LDS buffer reuse.
__global__ __launch_bounds__(256) void attn_kernel(const u16* __restrict__ qb,
                                                   const u16* __restrict__ kb,
                                                   const u16* __restrict__ vbT,
                                                   const float* __restrict__ Wt,
                                                   u16* __restrict__ Ob) {
  __shared__ __align__(16) u16 ldsK[2][64 * 128];
  __shared__ __align__(16) u16 ldsVT[2][128 * 64];
  __shared__ __align__(16) u16 ldsP[128 * 64];
  const int t = threadIdx.x;
  const int lane = t & 63, wid = t >> 6;
  const int lr = lane & 15, lg = lane >> 4;
  const int hb = blockIdx.y;  // h*16 + b
  const int b = hb & 15;
  const int h = hb >> 4;
  const int q0 = blockIdx.x * 128;
  const int wq = wid * 32;
  const size_t kvbase = ((size_t)b * 1024) * 512 + h * 128;
  const size_t vtbase = ((size_t)b * 4 + h) * 131072;  // V^T [128 d][1024 k]
  const float SCALE = 0.044194173824159216f;           // 1/sqrt(512)

  // staging: global source PRE-SWIZZLED, LDS dest linear
  const u16* ksrc[4];
  const u16* vtsrc[4];
#pragma unroll
  for (int i = 0; i < 4; ++i) {
    {  // K: [64 rows][128 cols], slot swizzle u^(row&15)
      int lin = i * 256 + t;
      int row = lin >> 4, u = lin & 15;
      ksrc[i] = kb + kvbase + (size_t)row * 512 + ((u ^ (row & 15)) * 8);
    }
    {  // V^T: [128 rows][64 cols], slot swizzle u^(row&7)
      int lin = i * 256 + t;
      int row = lin >> 3, u = lin & 7;
      vtsrc[i] = vbT + vtbase + (size_t)row * 1024 + ((u ^ (row & 7)) * 8);
    }
  }
  const int wslot = (t & 192) * 8;  // wave-uniform LDS element base

#define STAGE(bu)                                                                           \
  do {                                                                                      \
    _Pragma("unroll") for (int i_ = 0; i_ < 4; ++i_) {                                      \
      __builtin_amdgcn_global_load_lds((g32c*)(ksrc[i_]),                                   \
                                       (lds32*)(&ldsK[bu][i_ * 2048 + wslot]), 16, 0, 0);   \
      __builtin_amdgcn_global_load_lds((g32c*)(vtsrc[i_]),                                  \
                                       (lds32*)(&ldsVT[bu][i_ * 2048 + wslot]), 16, 0, 0);  \
      ksrc[i_] += 32768;  /* next 64 k-rows */                                              \
      vtsrc[i_] += 64;    /* next 64 k-cols */                                              \
    }                                                                                       \
  } while (0)

  // Wt prior: plain vector loads, one tile (8x f32x4/lane)
  const float* wp0 = Wt + ((size_t)hb * 1024 + q0 + wq + lr) * 1024 + lg * 4;  // nf=0 rows
  const float* wp1 = wp0 + 16 * 1024;                                          // nf=1 rows

#define WLOADP(W)                                          \
  do {                                                     \
    _Pragma("unroll") for (int j_ = 0; j_ < 4; ++j_) {     \
      W[j_]     = *(const f32x4*)(wp0 + j_ * 16);          \
      W[4 + j_] = *(const f32x4*)(wp1 + j_ * 16);          \
    }                                                      \
    wp0 += 64; wp1 += 64;                                  \
  } while (0)

  // Q fragments (B-operand of swapped QK^T), held in registers for all tiles
  short8 qfr[2][4];
#pragma unroll
  for (int nf = 0; nf < 2; ++nf) {
    const u16* qp = qb + kvbase + (size_t)(q0 + wq + nf * 16 + lr) * 512 + lg * 8;
#pragma unroll
    for (int ds = 0; ds < 4; ++ds) qfr[nf][ds] = *(const short8*)(qp + ds * 32);
  }

  f32x4 oacc[2][8];
#pragma unroll
  for (int i = 0; i < 2; ++i)
#pragma unroll
    for (int j = 0; j < 8; ++j)
#pragma unroll
      for (int r = 0; r < 4; ++r) oacc[i][j][r] = 0.f;
  float lacc[2] = {0.f, 0.f};

  auto tile_compute = [&](const u16* bK, const u16* bVT, const f32x4 (&W)[8]) {
    f32x4 sacc[4][2];
#pragma unroll
    for (int i = 0; i < 4; ++i)
#pragma unroll
      for (int j = 0; j < 2; ++j)
#pragma unroll
        for (int r = 0; r < 4; ++r) sacc[i][j][r] = 0.f;

#pragma unroll
    for (int ds = 0; ds < 4; ++ds) {
      short8 kf[4];
#pragma unroll
      for (int mf = 0; mf < 4; ++mf) {
        int row = mf * 16 + lr;
        kf[mf] = *(const short8*)&bK[row * 128 + (((ds * 4 + lg) ^ (row & 15)) * 8)];
      }
#pragma unroll
      for (int mf = 0; mf < 4; ++mf)
#pragma unroll
        for (int nf = 0; nf < 2; ++nf)
          sacc[mf][nf] =
              __builtin_amdgcn_mfma_f32_16x16x32_bf16(kf[mf], qfr[nf][ds], sacc[mf][nf], 0, 0, 0);
    }

#pragma unroll
    for (int nf = 0; nf < 2; ++nf) {
      int prow = wq + nf * 16 + lr;  // lane's q column of S^T
#pragma unroll
      for (int mf = 0; mf < 4; ++mf) {
        f32x4 w4 = W[nf * 4 + mf];  // prior for k = kt + mf*16 + lg*4 + {0..3}
        float p0 = w4[0] * __expf(sacc[mf][nf][0] * SCALE);
        float p1 = w4[1] * __expf(sacc[mf][nf][1] * SCALE);
        float p2 = w4[2] * __expf(sacc[mf][nf][2] * SCALE);
        float p3 = w4[3] * __expf(sacc[mf][nf][3] * SCALE);
        lacc[nf] += (p0 + p1) + (p2 + p3);
        uintx2 pk;
        pk[0] = (u32)f2bf(p0) | ((u32)f2bf(p1) << 16);
        pk[1] = (u32)f2bf(p2) | ((u32)f2bf(p3) << 16);
        int byteoff = (prow * 128 + (mf * 16 + lg * 4) * 2) ^ ((prow & 7) << 4);
        *(uintx2*)((char*)ldsP + byteoff) = pk;
      }
    }
    // each wave reads back only its own P rows; same-wave DS ops are in-order

#pragma unroll
    for (int ks = 0; ks < 2; ++ks) {
      short8 pa[2];
#pragma unroll
      for (int qf = 0; qf < 2; ++qf) {
        int row = wq + qf * 16 + lr;
        int byteoff = (row * 128 + (ks * 4 + lg) * 16) ^ ((row & 7) << 4);
        pa[qf] = *(const short8*)((const char*)ldsP + byteoff);
      }
      short8 vf[8];
#pragma unroll
      for (int nf = 0; nf < 8; ++nf) {
        int row = nf * 16 + lr;  // d
        vf[nf] = *(const short8*)&bVT[row * 64 + (((ks * 4 + lg) ^ (row & 7)) * 8)];
      }
#pragma unroll
      for (int qf = 0; qf < 2; ++qf)
#pragma unroll
        for (int nf = 0; nf < 8; ++nf)
          oacc[qf][nf] =
              __builtin_amdgcn_mfma_f32_16x16x32_bf16(pa[qf], vf[nf], oacc[qf][nf], 0, 0, 0);
    }
  };

#define SCHED_FENCE() __builtin_amdgcn_sched_barrier(0)
#define WAITBAR(N)                                                 \
  do {                                                             \
    SCHED_FENCE();                                                 \
    asm volatile("s_waitcnt vmcnt(" #N ")" ::: "memory");          \
    __builtin_amdgcn_s_barrier();                                  \
    SCHED_FENCE();                                                 \
  } while (0)
#define BAR()                                                      \
  do {                                                             \
    SCHED_FENCE();                                                 \
    __builtin_amdgcn_s_barrier();                                  \
    SCHED_FENCE();                                                 \
  } while (0)

  f32x4 wA[8], wB[8];
  WLOADP(wA);  // W(0)
  STAGE(0);    // KV(0)

  for (int it = 0; it < 8; ++it) {
    {  // even tile 2it in buf0, prior wA
      STAGE(1);                     // KV(2it+1)
      WLOADP(wB);                   // W(2it+1)
      WAITBAR(16);                  // drains KV(2it)+wA; leaves KV(2it+1)+wB in flight
      tile_compute(&ldsK[0][0], &ldsVT[0][0], wA);
      BAR();                        // buf0 reads complete before re-stage
    }
    {  // odd tile 2it+1 in buf1, prior wB
      if (it < 7) {
        STAGE(0);                   // KV(2it+2)
        WLOADP(wA);                 // W(2it+2)
        WAITBAR(16);                // drains KV(2it+1)+wB
      } else {
        WAITBAR(0);                 // last tile: drain everything
      }
      tile_compute(&ldsK[1][0], &ldsVT[1][0], wB);
      if (it < 7) BAR();
    }
  }

  // reduce l across the 4 lane-groups (disjoint k subsets for the same q)
  float lred[2];
#pragma unroll
  for (int nf = 0; nf < 2; ++nf) {
    float s = lacc[nf];
    s += __shfl_xor(s, 16);
    s += __shfl_xor(s, 32);
    lred[nf] = s;
  }

  // epilogue: O = q + oacc / l   (O-layout: col=lane&15, row=(lane>>4)*4+reg)
#pragma unroll
  for (int qf = 0; qf < 2; ++qf)
#pragma unroll
    for (int r = 0; r < 4; ++r) {
      float lv = __shfl(lred[qf], (lane & 48) | (lg * 4 + r));
      float linv = 1.0f / lv;
      int qrow = q0 + wq + qf * 16 + lg * 4 + r;
      size_t base = kvbase + (size_t)qrow * 512;
#pragma unroll
      for (int nf = 0; nf < 8; ++nf) {
        size_t idx = base + nf * 16 + lr;
        Ob[idx] = f2bf(bf2f(qb[idx]) + oacc[qf][nf][r] * linv);
      }
    }
#undef STAGE
#undef WLOADP
#undef WAITBAR
#undef BAR
#undef SCHED_FENCE
}

// ---------------- row LayerNorm over 512 cols (bf16 in, bf16 or f32 out) -----
template <bool F32OUT>
__global__ __launch_bounds__(256) void ln_kernel(const u16* __restrict__ in,
                                                 const float* __restrict__ g,
                                                 const float* __restrict__ be,
                                                 void* __restrict__ outp) {
  const int lane = threadIdx.x & 63, wid = threadIdx.x >> 6;
  const int row = blockIdx.x * 4 + wid;
  const u16* p = in + (size_t)row * 512 + lane * 8;
  short8 v = *(const short8*)p;
  float x[8];
  float s = 0.f, s2 = 0.f;
#pragma unroll
  for (int j = 0; j < 8; ++j) {
    x[j] = bf2f((u16)v[j]);
    s += x[j];
    s2 += x[j] * x[j];
  }
#pragma unroll
  for (int off = 1; off < 64; off <<= 1) {
    s += __shfl_xor(s, off);
    s2 += __shfl_xor(s2, off);
  }
  float mu = s * (1.f / 512.f);
  float var = s2 * (1.f / 512.f) - mu * mu;  // biased, matches jnp.var
  float rs = rsqrtf(var + 1e-5f);
  float4 ga = *(const float4*)(g + lane * 8);
  float4 gb = *(const float4*)(g + lane * 8 + 4);
  float4 ba = *(const float4*)(be + lane * 8);
  float4 bb = *(const float4*)(be + lane * 8 + 4);
  float gg[8] = {ga.x, ga.y, ga.z, ga.w, gb.x, gb.y, gb.z, gb.w};
  float bv[8] = {ba.x, ba.y, ba.z, ba.w, bb.x, bb.y, bb.z, bb.w};
  if constexpr (F32OUT) {
    float* out = (float*)outp + (size_t)row * 512 + lane * 8;
    float4 o0, o1;
    o0.x = (x[0] - mu) * rs * gg[0] + bv[0];
    o0.y = (x[1] - mu) * rs * gg[1] + bv[1];
    o0.z = (x[2] - mu) * rs * gg[2] + bv[2];
    o0.w = (x[3] - mu) * rs * gg[3] + bv[3];
    o1.x = (x[4] - mu) * rs * gg[4] + bv[4];
    o1.y = (x[5] - mu) * rs * gg[5] + bv[5];
    o1.z = (x[6] - mu) * rs * gg[6] + bv[6];
    o1.w = (x[7] - mu) * rs * gg[7] + bv[7];
    *(float4*)out = o0;
    *(float4*)(out + 4) = o1;
  } else {
    short8 o;
#pragma unroll
    for (int j = 0; j < 8; ++j) o[j] = (short)f2bf((x[j] - mu) * rs * gg[j] + bv[j]);
    *(short8*)((u16*)outp + (size_t)row * 512 + lane * 8) = o;
  }
}

extern "C" void kernel_launch(void* const* d_in, const int* in_sizes, int n_in,
                              void* d_out, int out_size, void* d_ws, size_t ws_size,
                              hipStream_t stream) {
  (void)in_sizes; (void)n_in; (void)out_size; (void)ws_size;
  const float* Q   = (const float*)d_in[0];
  const float* K   = (const float*)d_in[1];
  const float* Wt  = (const float*)d_in[2];
  const float* Wq  = (const float*)d_in[3];
  const float* bq  = (const float*)d_in[4];
  const float* Wk  = (const float*)d_in[5];
  const float* bk  = (const float*)d_in[6];
  const float* Wv  = (const float*)d_in[7];
  const float* bv  = (const float*)d_in[8];
  const float* Wo  = (const float*)d_in[9];
  const float* bo  = (const float*)d_in[10];
  const float* g0  = (const float*)d_in[11];
  const float* be0 = (const float*)d_in[12];
  const float* g1  = (const float*)d_in[13];
  const float* be1 = (const float*)d_in[14];

  char* ws = (char*)d_ws;
  const size_t MB16 = 16777216;
  u16* qb  = (u16*)(ws);
  u16* kb  = (u16*)(ws + MB16);
  u16* vbT = (u16*)(ws + 2 * MB16);  // V^T per head [64][128][1024]
  u16* Wb  = (u16*)(ws + 3 * MB16);
  u16* Ob  = (u16*)d_out;

  cvt_w_kernel<<<dim3(256, 4), 256, 0, stream>>>(Wq, Wk, Wv, Wo, Wb);
  gemm3_kernel<<<dim3(4, 128, 3), 256, 0, stream>>>(Q, K, Wb, bq, bk, bv, qb, kb, vbT);
  attn_kernel<<<dim3(8, 64), 256, 0, stream>>>(qb, kb, vbT, Wt, Ob);
  ln_kernel<false><<<4096, 256, 0, stream>>>(Ob, g0, be0, qb);
  gemmo_kernel<<<dim3(4, 128), 256, 0, stream>>>(qb, Wb + 786432, bo, kb);
  ln_kernel<true><<<4096, 256, 0, stream>>>(kb, g1, be1, d_out);
}